// Round 5
// baseline (1060.663 us; speedup 1.0000x reference)
//
#include <hip/hip_runtime.h>
#include <hip/hip_cooperative_groups.h>
#include <math.h>

namespace cg = cooperative_groups;

#define NPTS  16384
#define KNN   16
#define SEQV  8
#define NW    16      // waves per block
#define BATCH 8
#define CAPM  15      // append words/thread (flush thr -> max idx 14)
#define CAPR  1.001f  // radius cap in d2 space (d2>1 neighbors map to self)
#define NBKT  256
#define BSCALE 56.8888f   // NBKT / 4.5 norm range
#define NGRP  256     // query groups of 64
#define NITEM 512     // scan items = group x half-window
#define G0    133     // LPT center: most expensive (densest-norm) group

// Transposed LDS slot: row t (0..15), column col (0..1023).
#define SLOT(arr, t, col) arr[(t) * 1024 + (col)]

// ws layout (bytes): accum 0..255 | hist 256KB | sorted 256KB | keybuf 2MB
#define WS_HIST   256
#define WS_SORTED (WS_HIST + NBKT * NGRP * 4)
#define WS_KEYB   (WS_SORTED + (NPTS + 8) * 16)

__device__ __forceinline__ unsigned umin_(unsigned a, unsigned b) { return a < b ? a : b; }
__device__ __forceinline__ unsigned umax_(unsigned a, unsigned b) { return a > b ? a : b; }

// norm -> bucket, monotone; shared by scatter & window math (consistency!)
__device__ __forceinline__ int nbucket(float x) { return (int)fminf(x * BSCALE, 255.0f); }

// merge one key into sorted ascending keys[16] (scan-path flushes only)
__device__ __forceinline__ void merge_one(unsigned keys[KNN], unsigned kk) {
    if (kk < keys[KNN - 1]) {
#pragma unroll
        for (int u = 0; u < KNN; ++u) {
            unsigned lo = umin_(kk, keys[u]);
            kk = umax_(kk, keys[u]);
            keys[u] = lo;
        }
    }
}

// Exact top-16 of two sorted-ascending 16-lists (bitonic, ~80 unpredicated ops)
__device__ __forceinline__ void merge16(unsigned k[KNN], const unsigned o[KNN]) {
    unsigned v[KNN];
#pragma unroll
    for (int i = 0; i < KNN; ++i) v[i] = umin_(k[i], o[KNN - 1 - i]);
#pragma unroll
    for (int d = 8; d >= 1; d >>= 1) {
#pragma unroll
        for (int i = 0; i < KNN; ++i) {
            if ((i & d) == 0) {
                unsigned lo = umin_(v[i], v[i + d]);
                unsigned hi = umax_(v[i], v[i + d]);
                v[i] = lo; v[i + d] = hi;
            }
        }
    }
#pragma unroll
    for (int i = 0; i < KNN; ++i) k[i] = v[i];
}

__device__ __forceinline__ void tree_load_merge(unsigned* uS, unsigned keys[KNN], int src) {
    unsigned o[KNN];
#pragma unroll
    for (int t = 0; t < KNN; ++t) o[t] = SLOT(uS, t, src);
    merge16(keys, o);
}

// ---------------------------------------------------------------------------
// Single cooperative kernel, grid 256 x 1024 (1 block/CU, all co-resident).
// Stage 0: per-block histogram row of its 64 points (bin-major hist table).
// Stage 1: every block redundantly computes bin starts (prefix in LDS, kept
//   for windowing); deterministic scatter: pos = starts[bin] +
//   (count in blocks < b) + rank-within-block. No global atomics, no memset.
// Stage 3: 512 scan items (group, half-window) popped center-out from a
//   global queue (LPT-ish balance). Per item: analytic-tau'd quarter-sample
//   scan -> tree merge -> exact sample d16 + certificate (fallback CAPR /
//   full-range, provably sufficient) -> filtered half-window scan -> tree
//   merge -> write 16x64 keys to keybuf. Independent per-half certs are
//   safe: tau_h >= half-true d16 >= merged d16.
// Stage 4: block b merges group b's halves (merge16), radius-maps
//   (NaN-robust: sentinel -> self), then loss + reduce + finalize.
// key = (d2 bits & 0xFFFFC000) | orig_idx (idx < 2^14).
// accum[0]=loss, [1]=wsum, [2]=finalize ticket, [3]=scan queue.
// ---------------------------------------------------------------------------
__global__ __launch_bounds__(1024, 4) void mega_kernel(
    const float* __restrict__ pc, const float* __restrict__ flow,
    const float* __restrict__ wts, float* __restrict__ ws,
    float* __restrict__ out)
{
    __shared__ unsigned uS[1024 * 16];   // 64 KB union: scan bufs / merge / ids
    __shared__ unsigned sS[NBKT + 1];    // bin starts (persists through stage 3)
    __shared__ unsigned sB[NBKT];        // local hist -> scatter offsets
    __shared__ unsigned sPop[1];
    float* sred = (float*)&uS[15 * 1024 + 1000];   // stage-4 only
    float* sTau = (float*)&uS[16320];              // item tree1-end..PhaseA

    float*    accum   = ws;
    unsigned* hist    = (unsigned*)((char*)ws + WS_HIST);
    float4*   sorted4 = (float4*)  ((char*)ws + WS_SORTED);
    unsigned* keybuf  = (unsigned*)((char*)ws + WS_KEYB);

    cg::grid_group grid = cg::this_grid();

    const int tid  = threadIdx.x;
    const int lane = tid & 63;
    const int wv   = __builtin_amdgcn_readfirstlane(tid >> 6);   // 0..15
    const int b    = blockIdx.x;

    // ========== stage 0: histogram row + zero accum =======================
    float px = 0.0f, py = 0.0f, pz = 0.0f;
    int pv = 0; unsigned prank = 0;
    if (tid < NBKT) sB[tid] = 0u;
    if (b == 0 && tid < 8) ((unsigned*)accum)[tid] = 0u;
    __syncthreads();
    if (tid < 64) {
        const int i = b * 64 + lane;
        px = pc[3 * i + 0]; py = pc[3 * i + 1]; pz = pc[3 * i + 2];
        const float n = sqrtf(fmaf(px, px, fmaf(py, py, pz * pz)));
        pv = nbucket(n);
        prank = atomicAdd(&sB[pv], 1u);    // rank of this point within block
    }
    __syncthreads();
    if (tid < NBKT) hist[tid * NGRP + b] = sB[tid];
    grid.sync();

    // ========== stage 1: starts (all blocks) + deterministic scatter ======
    unsigned c0 = 0, pre0 = 0;
    if (tid < NBKT) {
        const unsigned* row = hist + tid * NGRP;
        unsigned s = 0, pre = 0;
#pragma unroll 4
        for (int k = 0; k < NGRP; ++k) {
            const unsigned c = row[k];
            if (k < b) pre += c;
            s += c;
        }
        c0 = s; pre0 = pre;
        sS[tid] = s;
    }
    __syncthreads();
    for (int off = 1; off < NBKT; off <<= 1) {     // inclusive scan
        unsigned a = 0u;
        if (tid < NBKT && tid >= off) a = sS[tid - off];
        __syncthreads();
        if (tid < NBKT) sS[tid] += a;
        __syncthreads();
    }
    if (tid < NBKT) {
        const unsigned excl = sS[tid] - c0;
        sB[tid] = excl + pre0;     // this block's scatter base per bin
        sS[tid] = excl;            // global starts
    }
    if (tid == 0) sS[NBKT] = NPTS;
    __syncthreads();
    if (tid < 64) {
        const unsigned pos = sB[pv] + prank;
        sorted4[pos] = make_float4(px, py, pz,
                                   __uint_as_float((unsigned)(b * 64 + lane)));
    }
    if (b == 0 && tid < 8)
        sorted4[NPTS + tid] = make_float4(1e18f, 1e18f, 1e18f, __uint_as_float(0u));
    grid.sync();

    // ========== stage 3: scan items via LPT pop-queue =====================
    while (true) {
        if (tid == 0) sPop[0] = atomicAdd((unsigned*)accum + 3, 1u);
        __syncthreads();
        const unsigned tk = sPop[0];
        __syncthreads();
        if (tk >= NITEM) break;
        const int h = (int)(tk & 1u);
        const int u = (int)(tk >> 1);
        int g = (u & 1) ? (G0 + ((u + 1) >> 1)) : (G0 - (u >> 1));
        g &= 255;                                   // bijective center-out

        const float4 q4 = sorted4[g * 64 + lane];
        const float qx = q4.x, qy = q4.y, qz = q4.z;
        const float q2 = fmaf(qx, qx, fmaf(qy, qy, qz * qz));
        const float analytic = 0.19072f * exp2f(0.480898f * q2);  // 8x E[d16^2]
        const float tau0 = fminf(analytic, CAPR);
        const float nq = sqrtf(q2);
        float nmin = nq, nmax = nq;
#pragma unroll
        for (int off = 32; off > 0; off >>= 1) {
            nmin = fminf(nmin, __shfl_xor(nmin, off));
            nmax = fmaxf(nmax, __shfl_xor(nmax, off));
        }
        const float r0 = sqrtf(fminf(0.19072f * exp2f(0.480898f * nmax * nmax), CAPR));
        const int blo = nbucket(fmaxf(nmin - r0, 0.0f));
        const int bhi = nbucket(nmax + r0);
        const int W0  = (int)__builtin_amdgcn_readfirstlane(sS[blo]);
        const int W1  = (int)__builtin_amdgcn_readfirstlane(sS[bhi + 1]);
        const int nbt = (W1 - W0 + 7) >> 3;
        const int nbH = (nbt + 1) >> 1;

        unsigned keys[KNN];
#pragma unroll
        for (int t = 0; t < KNN; ++t) keys[t] = 0xFFFFFFFFu;
        int cnt = 0;
        unsigned* buf = &uS[tid * CAPM];            // stride 15 -> spread banks

        // ---- tau phase: quarter-sample of own half ----
        {
            float tauT = tau0;
            const float4* cb = sorted4 + W0;
            const int bt1 = h ? nbt : nbH;
            float4 A[BATCH], Bv[BATCH];
            auto procT = [&](const float4* C) {
#pragma unroll
                for (int q = 0; q < BATCH; ++q) {
                    const float4 c = C[q];
                    const float dx = qx - c.x, dy = qy - c.y, dz = qz - c.z;
                    const float d2 = fmaf(dx, dx, fmaf(dy, dy, dz * dz));
                    const bool acc = d2 <= tauT;
                    if (__any(acc)) {               // wave-rare branch
                        if (acc) {
                            buf[cnt] = (__float_as_uint(d2) & 0xFFFFC000u)
                                     | __float_as_uint(c.w);   // orig idx
                            ++cnt;
                        }
                        if (cnt >= CAPM - 1) {
#pragma unroll 1
                            for (int t = 0; t < cnt; ++t) merge_one(keys, buf[t]);
                            cnt = 0;
                            const float d16n = __uint_as_float(keys[KNN - 1] & 0xFFFFC000u);
                            tauT = fminf(tauT, fmaf(d16n, 1.0002f, 1e-6f));
                        }
                    }
                }
            };
            int gb = (h ? nbH : 0) + wv;
            bool hA = (gb < bt1);
            if (hA) { const float4* bp = cb + 8 * gb;
#pragma unroll
                for (int q = 0; q < BATCH; ++q) A[q] = bp[q]; }
            while (hA) {
                const int g2 = gb + 64; const bool hB = (g2 < bt1);
                if (hB) { const float4* bp = cb + 8 * g2;
#pragma unroll
                    for (int q = 0; q < BATCH; ++q) Bv[q] = bp[q]; }
                procT(A);
                if (!hB) break;
                const int g3 = g2 + 64; const bool hC = (g3 < bt1);
                if (hC) { const float4* bp = cb + 8 * g3;
#pragma unroll
                    for (int q = 0; q < BATCH; ++q) A[q] = bp[q]; }
                procT(Bv);
                gb = g3; hA = hC;
            }
#pragma unroll 1
            for (int t = 0; t < cnt; ++t) merge_one(keys, buf[t]);
            cnt = 0;
        }
        __syncthreads();   // bufs dead; reuse uS as transposed merge slots

        // ---- tree merge 1 -> exact sample tau + certificate ----
#pragma unroll
        for (int t = 0; t < KNN; ++t) SLOT(uS, t, tid) = keys[t];
        __syncthreads();
        if (wv < 8) {
            tree_load_merge(uS, keys, tid + 512);
#pragma unroll
            for (int t = 0; t < KNN; ++t) SLOT(uS, t, tid) = keys[t];
        }
        __syncthreads();
        if (wv < 4) {
            tree_load_merge(uS, keys, tid + 256);
#pragma unroll
            for (int t = 0; t < KNN; ++t) SLOT(uS, t, tid) = keys[t];
        }
        __syncthreads();
        if (wv < 2) {
            tree_load_merge(uS, keys, tid + 128);
#pragma unroll
            for (int t = 0; t < KNN; ++t) SLOT(uS, t, tid) = keys[t];
        }
        __syncthreads();
        if (wv == 0) {
            tree_load_merge(uS, keys, tid + 64);
            const float d16 = __uint_as_float(keys[KNN - 1] & 0xFFFFC000u);
            const float tf  = fmaf(d16, 1.0002f, 1e-6f);
            const bool fail = !(tf <= tau0);        // NaN sentinel -> fail
            const float tv = fail ? CAPR : tf;
            sTau[lane] = tv;
            float tm = tv;
#pragma unroll
            for (int off = 32; off > 0; off >>= 1) tm = fmaxf(tm, __shfl_xor(tm, off));
            const unsigned long long bw = __ballot(fail && (analytic < CAPR));
            if (lane == 0) { uS[16316] = (bw != 0ull) ? 1u : 0u; ((float*)uS)[16317] = tm; }
        }
        __syncthreads();

        // ---- phase A: filtered scan of own half of the tight window ----
        float tauf = sTau[lane];
        const unsigned anyWide = __builtin_amdgcn_readfirstlane(uS[16316]);
        const float rA = sqrtf(((float*)uS)[16317]);
        int W0A, nbtA;
        if (anyWide) { W0A = 0; nbtA = NPTS / 8; }
        else {
            const int bloA = nbucket(fmaxf(nmin - rA, 0.0f));
            const int bhiA = nbucket(nmax + rA);
            W0A = (int)__builtin_amdgcn_readfirstlane(sS[bloA]);
            const int W1A = (int)__builtin_amdgcn_readfirstlane(sS[bhiA + 1]);
            nbtA = (W1A - W0A + 7) >> 3;
        }
        const int nbAH = (nbtA + 1) >> 1;
#pragma unroll
        for (int t = 0; t < KNN; ++t) keys[t] = 0xFFFFFFFFu;
        {
            const float4* cb = sorted4 + W0A;
            const int bt1 = h ? nbtA : nbAH;
            float4 A[BATCH], Bv[BATCH];
            auto procA = [&](const float4* C) {
#pragma unroll
                for (int q = 0; q < BATCH; ++q) {
                    const float4 c = C[q];
                    const float dx = qx - c.x, dy = qy - c.y, dz = qz - c.z;
                    const float d2 = fmaf(dx, dx, fmaf(dy, dy, dz * dz));
                    const bool acc = d2 <= tauf;
                    if (__any(acc)) {               // wave-rare branch
                        if (acc) {
                            buf[cnt] = (__float_as_uint(d2) & 0xFFFFC000u)
                                     | __float_as_uint(c.w);   // orig idx
                            ++cnt;
                        }
                        if (cnt >= CAPM - 1) {
#pragma unroll 1
                            for (int t = 0; t < cnt; ++t) merge_one(keys, buf[t]);
                            cnt = 0;
                            const float d16n = __uint_as_float(keys[KNN - 1] & 0xFFFFC000u);
                            tauf = fminf(tauf, fmaf(d16n, 1.0002f, 1e-6f));
                        }
                    }
                }
            };
            int gb = (h ? nbAH : 0) + wv;
            bool hA = (gb < bt1);
            if (hA) { const float4* bp = cb + 8 * gb;
#pragma unroll
                for (int q = 0; q < BATCH; ++q) A[q] = bp[q]; }
            while (hA) {
                const int g2 = gb + 16; const bool hB = (g2 < bt1);
                if (hB) { const float4* bp = cb + 8 * g2;
#pragma unroll
                    for (int q = 0; q < BATCH; ++q) Bv[q] = bp[q]; }
                procA(A);
                if (!hB) break;
                const int g3 = g2 + 16; const bool hC = (g3 < bt1);
                if (hC) { const float4* bp = cb + 8 * g3;
#pragma unroll
                    for (int q = 0; q < BATCH; ++q) A[q] = bp[q]; }
                procA(Bv);
                gb = g3; hA = hC;
            }
#pragma unroll 1
            for (int t = 0; t < cnt; ++t) merge_one(keys, buf[t]);
            cnt = 0;
        }
        __syncthreads();   // bufs dead; reuse uS for tree 2

        // ---- tree merge 2 -> exact half top-16 -> keybuf ----
#pragma unroll
        for (int t = 0; t < KNN; ++t) SLOT(uS, t, tid) = keys[t];
        __syncthreads();
        if (wv < 8) {
            tree_load_merge(uS, keys, tid + 512);
#pragma unroll
            for (int t = 0; t < KNN; ++t) SLOT(uS, t, tid) = keys[t];
        }
        __syncthreads();
        if (wv < 4) {
            tree_load_merge(uS, keys, tid + 256);
#pragma unroll
            for (int t = 0; t < KNN; ++t) SLOT(uS, t, tid) = keys[t];
        }
        __syncthreads();
        if (wv < 2) {
            tree_load_merge(uS, keys, tid + 128);
#pragma unroll
            for (int t = 0; t < KNN; ++t) SLOT(uS, t, tid) = keys[t];
        }
        __syncthreads();
        if (wv == 0) {
            tree_load_merge(uS, keys, tid + 64);
            unsigned* kb = keybuf + (size_t)(2 * g + h) * 1024;
#pragma unroll
            for (int t = 0; t < KNN; ++t) kb[t * 64 + lane] = keys[t];
        }
        __syncthreads();   // uS free for next item
    }
    grid.sync();

    // ========== stage 4: merge halves + radius -> ids + loss ==============
    {
        const float4 q4 = sorted4[b * 64 + lane];
        const unsigned iorig = __float_as_uint(q4.w);

        if (wv == 0) {
            unsigned keys[KNN], o[KNN];
            const unsigned* k0 = keybuf + (size_t)(2 * b + 0) * 1024;
            const unsigned* k1 = keybuf + (size_t)(2 * b + 1) * 1024;
#pragma unroll
            for (int t = 0; t < KNN; ++t) keys[t] = k0[t * 64 + lane];
#pragma unroll
            for (int t = 0; t < KNN; ++t) o[t] = k1[t * 64 + lane];
            merge16(keys, o);
            const int id0 = (int)(keys[0] & 0x3FFFu);   // nearest (self)
#pragma unroll
            for (int t = 0; t < KNN; ++t) {
                const float d2t = __uint_as_float(keys[t] & 0xFFFFC000u);
                const int   j   = (int)(keys[t] & 0x3FFFu);
                // ordered compare: NaN sentinel -> id0 (robust)
                SLOT(uS, t, lane) = (unsigned)((d2t <= 1.0f) ? j : id0);
            }
        }
        __syncthreads();

        const int s  = wv & 7;
        const int kh = wv >> 3;
        const float* fs = flow + (size_t)s * NPTS * 3;
        const float fx = fs[3 * iorig + 0];
        const float fy = fs[3 * iorig + 1];
        const float fz = fs[3 * iorig + 2];

        float sum = 0.0f;
#pragma unroll
        for (int z = 0; z < 8; ++z) {
            const int j = (int)SLOT(uS, kh * 8 + z, lane);   // conflict-free
            const float dx = fx - fs[3 * j + 0];
            const float dy = fy - fs[3 * j + 1];
            const float dz = fz - fs[3 * j + 2];
            const float sq = fmaf(dx, dx, fmaf(dy, dy, dz * dz));
            sum += (sq > 0.0f) ? sqrtf(sq) : 0.0f;
        }

        float contrib = wts[iorig] * sum;
#pragma unroll
        for (int off = 32; off > 0; off >>= 1) contrib += __shfl_down(contrib, off);
        if (lane == 0) sred[wv] = contrib;

        if (wv == 0) {                       // weight sum, once per block
            float wi = wts[iorig];
#pragma unroll
            for (int off = 32; off > 0; off >>= 1) wi += __shfl_down(wi, off);
            if (lane == 0) atomicAdd(&accum[1], wi);
        }
        __syncthreads();

        if (tid == 0) {
            float c = 0.0f;
#pragma unroll
            for (int t = 0; t < NW; ++t) c += sred[t];
            atomicAdd(&accum[0], c);
            __threadfence();
            const unsigned ticket = atomicAdd((unsigned*)accum + 2, 1u);
            if (ticket == gridDim.x - 1) {   // last block finalizes
                const float a  = atomicAdd(&accum[0], 0.0f);   // coherent read
                const float wsv = atomicAdd(&accum[1], 0.0f);
                const float v  = a / (float)(KNN * SEQV);
                out[0] = (wsv > 0.0f) ? (v / wsv) : v;
            }
        }
    }
}

extern "C" void kernel_launch(void* const* d_in, const int* in_sizes, int n_in,
                              void* d_out, int out_size, void* d_ws, size_t ws_size,
                              hipStream_t stream)
{
    const float* pc   = (const float*)d_in[0];   // (1, N, 3)
    const float* flow = (const float*)d_in[1];   // (SEQ, N, 3)
    const float* wts  = (const float*)d_in[2];   // (N,)
    float* out = (float*)d_out;
    float* ws  = (float*)d_ws;

    void* args[] = { (void*)&pc, (void*)&flow, (void*)&wts, (void*)&ws, (void*)&out };
    hipLaunchCooperativeKernel((const void*)mega_kernel, dim3(NGRP), dim3(1024),
                               args, 0, stream);
}

// Round 6
// 150.909 us; speedup vs baseline: 7.0285x; 7.0285x over previous
//
#include <hip/hip_runtime.h>
#include <math.h>

#define NPTS  16384
#define KNN   16
#define SEQV  8
#define NW    16      // waves per block
#define BATCH 8
#define CAPM  15      // append words/thread (flush thr -> max idx 14)
#define CAPR  1.001f  // radius cap in d2 space (d2>1 neighbors map to self)
#define NBKT  256
#define BSCALE 56.8888f   // NBKT / 4.5 norm range
#define HBLK  16      // hist/scatter blocks (1024 pts each)

// Transposed LDS slot: row t (0..15), column col (0..1023).
#define SLOT(arr, t, col) arr[(t) * 1024 + (col)]

// ws layout (bytes): accum 0..255 | hist 16KB | starts 1KB+ | sorted
#define WS_HIST   256
#define WS_STARTS (WS_HIST + NBKT * HBLK * 4)          // 16640
#define WS_SORTED 18432                                 // 16-byte aligned

__device__ __forceinline__ unsigned umin_(unsigned a, unsigned b) { return a < b ? a : b; }
__device__ __forceinline__ unsigned umax_(unsigned a, unsigned b) { return a > b ? a : b; }

// norm -> bucket, monotone; shared by scatter & window math (consistency!)
__device__ __forceinline__ int nbucket(float x) { return (int)fminf(x * BSCALE, 255.0f); }

// merge one key into sorted ascending keys[16] (scan-path flushes only)
__device__ __forceinline__ void merge_one(unsigned keys[KNN], unsigned kk) {
    if (kk < keys[KNN - 1]) {
#pragma unroll
        for (int u = 0; u < KNN; ++u) {
            unsigned lo = umin_(kk, keys[u]);
            kk = umax_(kk, keys[u]);
            keys[u] = lo;
        }
    }
}

// Exact top-16 of two sorted-ascending 16-lists (bitonic, ~80 unpredicated ops)
__device__ __forceinline__ void merge16(unsigned k[KNN], const unsigned o[KNN]) {
    unsigned v[KNN];
#pragma unroll
    for (int i = 0; i < KNN; ++i) v[i] = umin_(k[i], o[KNN - 1 - i]);
#pragma unroll
    for (int d = 8; d >= 1; d >>= 1) {
#pragma unroll
        for (int i = 0; i < KNN; ++i) {
            if ((i & d) == 0) {
                unsigned lo = umin_(v[i], v[i + d]);
                unsigned hi = umax_(v[i], v[i + d]);
                v[i] = lo; v[i + d] = hi;
            }
        }
    }
#pragma unroll
    for (int i = 0; i < KNN; ++i) k[i] = v[i];
}

__device__ __forceinline__ void tree_load_merge(unsigned* uS, unsigned keys[KNN], int src) {
    unsigned o[KNN];
#pragma unroll
    for (int t = 0; t < KNN; ++t) o[t] = SLOT(uS, t, src);
    merge16(keys, o);
}

// ---------------------------------------------------------------------------
// K1: per-block LDS histogram -> hist[bin * HBLK + blk]. No global atomics,
// no pre-zeroing (LDS zeroed locally) -> no hipMemsetAsync (SDMA sync ~50us).
// ---------------------------------------------------------------------------
__global__ __launch_bounds__(1024) void hist_kernel(
    const float* __restrict__ pc, unsigned* __restrict__ hist)
{
    __shared__ unsigned h[NBKT];
    const int tid = threadIdx.x;
    if (tid < NBKT) h[tid] = 0u;
    __syncthreads();
    const int i = blockIdx.x * 1024 + tid;
    const float x = pc[3 * i + 0], y = pc[3 * i + 1], z = pc[3 * i + 2];
    const float n = sqrtf(fmaf(x, x, fmaf(y, y, z * z)));
    atomicAdd(&h[nbucket(n)], 1u);
    __syncthreads();
    if (tid < NBKT) hist[tid * HBLK + blockIdx.x] = h[tid];
}

// ---------------------------------------------------------------------------
// K2: scatter. Each block redundantly computes the global prefix (16 KB hist
// table -> LDS scan), derives its own deterministic scatter base per bin
// (starts[bin] + count in earlier blocks), ranks its points via LDS atomics,
// writes sorted4 (w = orig index bits). Block 0 also publishes starts[] and
// zeroes accum (replaces the memset node). Sentinel pads at [NPTS, NPTS+8).
// ---------------------------------------------------------------------------
__global__ __launch_bounds__(1024) void scatter_kernel(
    const float* __restrict__ pc, const unsigned* __restrict__ hist,
    unsigned* __restrict__ starts, float* __restrict__ accum,
    float4* __restrict__ sorted4)
{
    __shared__ unsigned sH[NBKT];     // inclusive-scan workspace
    __shared__ unsigned sBase[NBKT];  // this block's scatter base per bin
    __shared__ unsigned sCnt[NBKT];   // rank atomics
    const int tid = threadIdx.x;
    const int b   = blockIdx.x;

    unsigned own = 0, pre = 0;
    if (tid < NBKT) {
        const unsigned* row = hist + tid * HBLK;
        unsigned s = 0, p = 0;
#pragma unroll
        for (int k = 0; k < HBLK; ++k) {
            const unsigned c = row[k];
            if (k < b) p += c;
            s += c;
        }
        own = s; pre = p;
        sH[tid] = s;
        sCnt[tid] = 0u;
    }
    __syncthreads();
    for (int off = 1; off < NBKT; off <<= 1) {        // Hillis-Steele inclusive
        unsigned a = 0u;
        if (tid < NBKT && tid >= off) a = sH[tid - off];
        __syncthreads();
        if (tid < NBKT) sH[tid] += a;
        __syncthreads();
    }
    if (tid < NBKT) {
        const unsigned excl = sH[tid] - own;
        sBase[tid] = excl + pre;
        if (b == 0) starts[tid] = excl;
    }
    if (b == 0 && tid == 0) starts[NBKT] = NPTS;
    if (b == 0 && tid < 8) ((unsigned*)accum)[tid] = 0u;   // loss/wsum/ticket
    __syncthreads();

    const int i = b * 1024 + tid;
    const float x = pc[3 * i + 0], y = pc[3 * i + 1], z = pc[3 * i + 2];
    const float n = sqrtf(fmaf(x, x, fmaf(y, y, z * z)));
    const int bin = nbucket(n);
    const unsigned rank = atomicAdd(&sCnt[bin], 1u);
    sorted4[sBase[bin] + rank] = make_float4(x, y, z, __uint_as_float((unsigned)i));
    if (b == 0 && tid < 8)
        sorted4[NPTS + tid] = make_float4(1e18f, 1e18f, 1e18f, __uint_as_float(0u));
}

// ---------------------------------------------------------------------------
// K3: windowed mega (BYTE-IDENTICAL to round 4's proven 97.6us kernel).
// Grid 256 x 1024; block = 64 norm-adjacent queries (lane = query), 16 waves
// share the block's candidate window. Triangle inequality prunes by norm.
// ---------------------------------------------------------------------------
__global__ __launch_bounds__(1024, 4) void mega_kernel(
    const float4* __restrict__ sorted, const unsigned* __restrict__ starts,
    const float* __restrict__ flow, const float* __restrict__ wts,
    float* __restrict__ accum, float* __restrict__ out)
{
    __shared__ unsigned uS[1024 * 16];   // 64 KB union: scan bufs / merge / ids
    float* sred = (float*)&uS[15 * 1024 + 1000];   // Phase C only
    float* sTau = (float*)&uS[16320];              // tree1-end .. Phase A
    // aux words 16316 (anyWide), 16317 (tauMax) — same lifetime as sTau

    const int tid  = threadIdx.x;
    const int lane = tid & 63;
    const int wv   = __builtin_amdgcn_readfirstlane(tid >> 6);   // 0..15
    const int is   = blockIdx.x * 64 + lane;       // sorted position

    const float4 q4 = sorted[is];
    const float qx = q4.x, qy = q4.y, qz = q4.z;
    const unsigned iorig = __float_as_uint(q4.w);
    const float q2 = fmaf(qx, qx, fmaf(qy, qy, qz * qz));
    const float analytic = 0.19072f * exp2f(0.480898f * q2);   // 8x E[d16^2]
    const float tau0 = fminf(analytic, CAPR);

    // wave min/max of the block's 64 query norms (identical in every wave)
    const float nq = sqrtf(q2);
    float nmin = nq, nmax = nq;
#pragma unroll
    for (int off = 32; off > 0; off >>= 1) {
        nmin = fminf(nmin, __shfl_xor(nmin, off));
        nmax = fmaxf(nmax, __shfl_xor(nmax, off));
    }
    // r0 from nmax (tau0 monotone in q2) — covers every lane's tau0-ball
    const float r0 = sqrtf(fminf(0.19072f * exp2f(0.480898f * nmax * nmax), CAPR));
    const int blo = nbucket(fmaxf(nmin - r0, 0.0f));
    const int bhi = nbucket(nmax + r0);
    const int W0  = __builtin_amdgcn_readfirstlane((int)starts[blo]);
    const int W1  = __builtin_amdgcn_readfirstlane((int)starts[bhi + 1]);
    const int nbt = (W1 - W0 + 7) >> 3;            // batches (pads cover tail)

    unsigned keys[KNN];
#pragma unroll
    for (int t = 0; t < KNN; ++t) keys[t] = 0xFFFFFFFFu;
    int cnt = 0;
    unsigned* buf = &uS[tid * CAPM];               // stride 15 -> spread banks

    // ================= Tau phase: every 4th super-batch ===================
    {
        float tauT = tau0;
        const float4* cb = sorted + W0;
        float4 A[BATCH], Bv[BATCH];

        auto procT = [&](const float4* C) {
#pragma unroll
            for (int q = 0; q < BATCH; ++q) {
                const float4 c = C[q];
                float dx = qx - c.x, dy = qy - c.y, dz = qz - c.z;
                float d2 = fmaf(dx, dx, fmaf(dy, dy, dz * dz));
                bool acc = d2 <= tauT;
                if (__any(acc)) {                    // wave-rare branch
                    if (acc) {
                        buf[cnt] = (__float_as_uint(d2) & 0xFFFFC000u)
                                 | __float_as_uint(c.w);   // ORIG idx
                        ++cnt;
                    }
                    if (cnt >= CAPM - 1) {
#pragma unroll 1
                        for (int t = 0; t < cnt; ++t) merge_one(keys, buf[t]);
                        cnt = 0;
                        float d16n = __uint_as_float(keys[KNN - 1] & 0xFFFFC000u);
                        tauT = fminf(tauT, fmaf(d16n, 1.0002f, 1e-6f));
                    }
                }
            }
        };

        int g = wv;
        bool hA = (g < nbt);
        if (hA) { const float4* bp = cb + 8 * g;
#pragma unroll
            for (int q = 0; q < BATCH; ++q) A[q] = bp[q]; }
        while (hA) {
            int g2 = g + 64;
            bool hB = (g2 < nbt);
            if (hB) { const float4* bp = cb + 8 * g2;
#pragma unroll
                for (int q = 0; q < BATCH; ++q) Bv[q] = bp[q]; }
            procT(A);
            if (!hB) break;
            int g3 = g2 + 64;
            bool hC = (g3 < nbt);
            if (hC) { const float4* bp = cb + 8 * g3;
#pragma unroll
                for (int q = 0; q < BATCH; ++q) A[q] = bp[q]; }
            procT(Bv);
            g = g3; hA = hC;
        }
#pragma unroll 1
        for (int t = 0; t < cnt; ++t) merge_one(keys, buf[t]);
        cnt = 0;
    }
    __syncthreads();   // bufs dead; reuse uS as transposed merge slots

    // ================= Tree merge 1 -> exact sample tau + Phase A window ==
#pragma unroll
    for (int t = 0; t < KNN; ++t) SLOT(uS, t, tid) = keys[t];
    __syncthreads();
    if (wv < 8) {
        tree_load_merge(uS, keys, tid + 512);
#pragma unroll
        for (int t = 0; t < KNN; ++t) SLOT(uS, t, tid) = keys[t];
    }
    __syncthreads();
    if (wv < 4) {
        tree_load_merge(uS, keys, tid + 256);
#pragma unroll
        for (int t = 0; t < KNN; ++t) SLOT(uS, t, tid) = keys[t];
    }
    __syncthreads();
    if (wv < 2) {
        tree_load_merge(uS, keys, tid + 128);
#pragma unroll
        for (int t = 0; t < KNN; ++t) SLOT(uS, t, tid) = keys[t];
    }
    __syncthreads();
    if (wv == 0) {
        tree_load_merge(uS, keys, tid + 64);
        const float d16 = __uint_as_float(keys[KNN - 1] & 0xFFFFC000u);
        const float tf  = fmaf(d16, 1.0002f, 1e-6f);
        // cert pass -> sample tau; fail (incl. NaN sentinel) -> radius cap.
        const bool fail = !(tf <= tau0);
        const float tv = fail ? CAPR : tf;
        sTau[lane] = tv;
        float tm = tv;
#pragma unroll
        for (int off = 32; off > 0; off >>= 1) tm = fmaxf(tm, __shfl_xor(tm, off));
        unsigned long long bw = __ballot(fail && (analytic < CAPR));
        if (lane == 0) { uS[16316] = (bw != 0ull) ? 1u : 0u; ((float*)uS)[16317] = tm; }
    }
    __syncthreads();

    // ================= Phase A: filtered scan of the tight window =========
    float tauf = sTau[lane];
    const unsigned anyWide = __builtin_amdgcn_readfirstlane(uS[16316]);
    const float rA = sqrtf(((float*)uS)[16317]);
    int W0A, nbtA;
    if (anyWide) { W0A = 0; nbtA = NPTS / 8; }
    else {
        int bloA = nbucket(fmaxf(nmin - rA, 0.0f));
        int bhiA = nbucket(nmax + rA);
        W0A = __builtin_amdgcn_readfirstlane((int)starts[bloA]);
        int W1A = __builtin_amdgcn_readfirstlane((int)starts[bhiA + 1]);
        nbtA = (W1A - W0A + 7) >> 3;
    }
#pragma unroll
    for (int t = 0; t < KNN; ++t) keys[t] = 0xFFFFFFFFu;
    {
        const float4* cb = sorted + W0A;
        float4 A[BATCH], Bv[BATCH];

        auto procA = [&](const float4* C) {
#pragma unroll
            for (int q = 0; q < BATCH; ++q) {
                const float4 c = C[q];
                float dx = qx - c.x, dy = qy - c.y, dz = qz - c.z;
                float d2 = fmaf(dx, dx, fmaf(dy, dy, dz * dz));
                bool acc = d2 <= tauf;
                if (__any(acc)) {                    // wave-rare branch
                    if (acc) {
                        buf[cnt] = (__float_as_uint(d2) & 0xFFFFC000u)
                                 | __float_as_uint(c.w);   // ORIG idx
                        ++cnt;
                    }
                    if (cnt >= CAPM - 1) {
#pragma unroll 1
                        for (int t = 0; t < cnt; ++t) merge_one(keys, buf[t]);
                        cnt = 0;
                        float d16n = __uint_as_float(keys[KNN - 1] & 0xFFFFC000u);
                        tauf = fminf(tauf, fmaf(d16n, 1.0002f, 1e-6f));
                    }
                }
            }
        };

        int g = wv;
        bool hA = (g < nbtA);
        if (hA) { const float4* bp = cb + 8 * g;
#pragma unroll
            for (int q = 0; q < BATCH; ++q) A[q] = bp[q]; }
        while (hA) {
            int g2 = g + 16;
            bool hB = (g2 < nbtA);
            if (hB) { const float4* bp = cb + 8 * g2;
#pragma unroll
                for (int q = 0; q < BATCH; ++q) Bv[q] = bp[q]; }
            procA(A);
            if (!hB) break;
            int g3 = g2 + 16;
            bool hC = (g3 < nbtA);
            if (hC) { const float4* bp = cb + 8 * g3;
#pragma unroll
                for (int q = 0; q < BATCH; ++q) A[q] = bp[q]; }
            procA(Bv);
            g = g3; hA = hC;
        }
#pragma unroll 1
        for (int t = 0; t < cnt; ++t) merge_one(keys, buf[t]);
    }
    __syncthreads();   // scan buffers dead; reuse uS for tree 2

    // ================= Phase B: tree merge + radius -> ids (orig) =========
#pragma unroll
    for (int t = 0; t < KNN; ++t) SLOT(uS, t, tid) = keys[t];
    __syncthreads();
    if (wv < 8) {
        tree_load_merge(uS, keys, tid + 512);
#pragma unroll
        for (int t = 0; t < KNN; ++t) SLOT(uS, t, tid) = keys[t];
    }
    __syncthreads();
    if (wv < 4) {
        tree_load_merge(uS, keys, tid + 256);
#pragma unroll
        for (int t = 0; t < KNN; ++t) SLOT(uS, t, tid) = keys[t];
    }
    __syncthreads();
    if (wv < 2) {
        tree_load_merge(uS, keys, tid + 128);
#pragma unroll
        for (int t = 0; t < KNN; ++t) SLOT(uS, t, tid) = keys[t];
    }
    __syncthreads();
    if (wv == 0) {
        tree_load_merge(uS, keys, tid + 64);
        const int id0 = (int)(keys[0] & 0x3FFFu);   // nearest (self, orig idx)
#pragma unroll
        for (int t = 0; t < KNN; ++t) {
            float d2t = __uint_as_float(keys[t] & 0xFFFFC000u);
            int   j   = (int)(keys[t] & 0x3FFFu);
            SLOT(uS, t, lane) = (unsigned)((d2t > 1.0f) ? id0 : j);
        }
    }
    __syncthreads();

    // ================= Phase C: loss + reduce + finalize ==================
    {
        const int s  = wv & 7;
        const int kh = wv >> 3;
        const float* fs = flow + (size_t)s * NPTS * 3;
        const float fx = fs[3 * iorig + 0];
        const float fy = fs[3 * iorig + 1];
        const float fz = fs[3 * iorig + 2];

        float sum = 0.0f;
#pragma unroll
        for (int z = 0; z < 8; ++z) {
            int j = (int)SLOT(uS, kh * 8 + z, lane);   // conflict-free
            float dx = fx - fs[3 * j + 0];
            float dy = fy - fs[3 * j + 1];
            float dz = fz - fs[3 * j + 2];
            float sq = fmaf(dx, dx, fmaf(dy, dy, dz * dz));
            sum += (sq > 0.0f) ? sqrtf(sq) : 0.0f;
        }

        float contrib = wts[iorig] * sum;
#pragma unroll
        for (int off = 32; off > 0; off >>= 1) contrib += __shfl_down(contrib, off);
        if (lane == 0) sred[wv] = contrib;

        if (wv == 0) {                       // weight sum, once per block
            float wi = wts[iorig];
#pragma unroll
            for (int off = 32; off > 0; off >>= 1) wi += __shfl_down(wi, off);
            if (lane == 0) atomicAdd(&accum[1], wi);
        }
        __syncthreads();

        if (tid == 0) {
            float c = 0.0f;
#pragma unroll
            for (int t = 0; t < NW; ++t) c += sred[t];
            atomicAdd(&accum[0], c);
            __threadfence();
            unsigned ticket = atomicAdd((unsigned*)accum + 2, 1u);
            if (ticket == gridDim.x - 1) {   // last block finalizes
                float a  = atomicAdd(&accum[0], 0.0f);   // coherent read
                float ws = atomicAdd(&accum[1], 0.0f);
                float v  = a / (float)(KNN * SEQV);
                out[0] = (ws > 0.0f) ? (v / ws) : v;
            }
        }
    }
}

extern "C" void kernel_launch(void* const* d_in, const int* in_sizes, int n_in,
                              void* d_out, int out_size, void* d_ws, size_t ws_size,
                              hipStream_t stream)
{
    const float* pc   = (const float*)d_in[0];   // (1, N, 3)
    const float* flow = (const float*)d_in[1];   // (SEQ, N, 3)
    const float* wts  = (const float*)d_in[2];   // (N,)
    float* out = (float*)d_out;

    float*    accum  = (float*)d_ws;
    unsigned* hist   = (unsigned*)((char*)d_ws + WS_HIST);
    unsigned* starts = (unsigned*)((char*)d_ws + WS_STARTS);
    float4*   sorted = (float4*)  ((char*)d_ws + WS_SORTED);

    // No hipMemsetAsync: SDMA<->compute sync inside the captured graph was
    // the ~50us gap (round 0: no memset, zero gap; rounds 3/4: 49/85us).
    hist_kernel   <<<HBLK, 1024, 0, stream>>>(pc, hist);
    scatter_kernel<<<HBLK, 1024, 0, stream>>>(pc, hist, starts, accum, sorted);
    mega_kernel   <<<NPTS / 64, 1024, 0, stream>>>(sorted, starts, flow, wts, accum, out);
}